// Round 8
// baseline (980.587 us; speedup 1.0000x reference)
//
#include <hip/hip_runtime.h>
#include <hip/hip_bf16.h>
#include <hip/hip_cooperative_groups.h>
#include <stdint.h>

namespace cg = cooperative_groups;

// GCNAE: N nodes, E edges, IN features, H hidden.
// Inputs fp32 (bf16-rounded values). Output fp32: adj [N,N] then z [N,H].
#define N_NODES 10000
#define N_EDGES 320000
#define DIM_IN  128
#define DIM_H   64
#define SSTR    72     // LDS row stride in shorts (64 + 8 pad -> 2-way banks only)
#define CSTR    132    // fp32 epilogue LDS stride (128 + 4 pad -> 2-way banks)
#define PBLOCKS 1024   // cooperative prologue grid (4 blocks/CU, safe capacity)
#define PTHREADS 256

typedef __attribute__((ext_vector_type(8))) short  short8;   // 8 bf16 (MFMA A/B frag)
typedef __attribute__((ext_vector_type(8))) unsigned short ushort8;
typedef __attribute__((ext_vector_type(4))) float  f32x4;    // MFMA C/D frag + stores

__device__ __forceinline__ unsigned short f2bf(float f) {
    union { float f; unsigned int i; } v; v.f = f;
    unsigned int u = v.i;
    return (unsigned short)((u + 0x7fffu + ((u >> 16) & 1u)) >> 16);  // RNE
}

// ---- prologue: ONE cooperative kernel, 5 phases ---------------------------
// R7 fusion: deg-zero+feat | hist | scan | bucket | agg with grid.sync()
// between phases. Replaces 6 dispatches (memset+5 kernels) -> 1; kills
// launch gaps and per-phase ramp/drain idle. Phase math is bit-identical
// to the R7 kernels (same loop orders), so absmax is unchanged.
__global__ void __launch_bounds__(PTHREADS) prologue_kernel(
    const float* __restrict__ x,
    const int*   __restrict__ ei,
    const float* __restrict__ ew,
    const float* __restrict__ wrel,
    const float* __restrict__ wroot,
    const float* __restrict__ bias,
    float*       __restrict__ out,        // d_out (z fp32 at N*N)
    unsigned short* __restrict__ zb,      // [N,64] bf16 z
    float*       __restrict__ xr,         // [N,64] x@W_rel
    float*       __restrict__ xw,         // [N,64] x@W_root + b
    int2*        __restrict__ swsrt,      // E packed {src, w_bits}
    int*         __restrict__ deg,
    int*         __restrict__ offs,
    int*         __restrict__ cursor)
{
    cg::grid_group grid = cg::this_grid();
    __shared__ float xLs[4][DIM_IN];      // 2 KB: 4 nodes/block in feat
    __shared__ int   part[PTHREADS];      // 1 KB: scan partials

    int t    = threadIdx.x;
    int wave = t >> 6;
    int lane = t & 63;
    int gid  = blockIdx.x * PTHREADS + t; // 0..262143

    // ---- P0: zero deg + feat (xr = x@W_rel, xw = x@W_root + b) ----
    if (gid < N_NODES) deg[gid] = 0;
    for (int base = blockIdx.x * 4; base < N_NODES; base += PBLOCKS * 4) {
        int node = base + wave;
        int nc = node < N_NODES ? node : N_NODES - 1;
        float2 xi = ((const float2*)(x + (size_t)nc * DIM_IN))[lane];
        xLs[wave][2 * lane]     = xi.x;
        xLs[wave][2 * lane + 1] = xi.y;
        __syncthreads();
        float ar = 0.f, aw = bias[lane];
        for (int k = 0; k < DIM_IN; ++k) {
            float xv = xLs[wave][k];
            ar += xv * wrel[k * DIM_H + lane];
            aw += xv * wroot[k * DIM_H + lane];
        }
        if (node < N_NODES) {
            xr[(size_t)node * DIM_H + lane] = ar;
            xw[(size_t)node * DIM_H + lane] = aw;
        }
        __syncthreads();                  // xLs reused next trip
    }
    grid.sync();

    // ---- P1: histogram of in-degrees ----
    for (int e = gid; e < N_EDGES; e += PBLOCKS * PTHREADS)
        atomicAdd(&deg[ei[N_EDGES + e]], 1);         // row 1 = dst
    grid.sync();

    // ---- P2: exclusive scan (block 0 only; 256 thr x 40 elems, 2-pass) ----
    if (blockIdx.x == 0) {
        const int PER = 40;               // 256*40 = 10240 >= N
        int base = t * PER;
        int s = 0;
        for (int k = 0; k < PER; ++k) {
            int idx = base + k;
            if (idx < N_NODES) s += deg[idx];
        }
        part[t] = s;
        __syncthreads();
        for (int o = 1; o < PTHREADS; o <<= 1) {
            int add = (t >= o) ? part[t - o] : 0;
            __syncthreads();
            part[t] += add;
            __syncthreads();
        }
        int run = part[t] - s;
        for (int k = 0; k < PER; ++k) {
            int idx = base + k;
            if (idx < N_NODES) {
                int d = deg[idx];
                offs[idx] = run; cursor[idx] = run; run += d;
            }
        }
        if (t == PTHREADS - 1) offs[N_NODES] = part[PTHREADS - 1];
    }
    grid.sync();

    // ---- P3: bucket edges into CSR with packed {src, w_bits} payload ----
    for (int e = gid; e < N_EDGES; e += PBLOCKS * PTHREADS) {
        int d = ei[N_EDGES + e];
        int slot = atomicAdd(&cursor[d], 1);
        int2 pay;
        pay.x = ei[e];                    // src
        pay.y = __float_as_int(ew[e]);    // weight bits
        swsrt[slot] = pay;
    }
    grid.sync();

    // ---- P4: aggregate z_i = sum_j w_ji*xr_j + xw_i (per-wave, 4-wide) ----
    int q   = lane >> 4;                  // edge slot 0..3
    int l16 = lane & 15;                  // feature quad id
    for (int i = blockIdx.x * 4 + wave; i < N_NODES; i += PBLOCKS * 4) {
        int beg = offs[i], end = offs[i + 1];
        f32x4 a = (f32x4)0.f;
        #pragma unroll 4
        for (int p = beg + q; p < end; p += 4) {
            int2 sw = swsrt[p];
            float w = __int_as_float(sw.y);
            f32x4 v = *(const f32x4*)(xr + (size_t)sw.x * DIM_H + l16 * 4);
            a += v * w;
        }
        f32x4 b;
        b.x = __shfl_xor(a.x, 16); b.y = __shfl_xor(a.y, 16);
        b.z = __shfl_xor(a.z, 16); b.w = __shfl_xor(a.w, 16);
        a += b;
        b.x = __shfl_xor(a.x, 32); b.y = __shfl_xor(a.y, 32);
        b.z = __shfl_xor(a.z, 32); b.w = __shfl_xor(a.w, 32);
        a += b;
        if (q == 0) {
            f32x4 w4 = *(const f32x4*)(xw + (size_t)i * DIM_H + l16 * 4);
            f32x4 z4 = a + w4;
            *(f32x4*)(out + (size_t)N_NODES * N_NODES + (size_t)i * DIM_H + l16 * 4) = z4;
            ushort4 h;
            h.x = f2bf(z4.x); h.y = f2bf(z4.y); h.z = f2bf(z4.z); h.w = f2bf(z4.w);
            *(ushort4*)(zb + (size_t)i * DIM_H + l16 * 4) = h;
        }
    }
}

// ---- gemm: adj = sigmoid(z @ z^T) -----------------------------------------
// Block tile 128x128, 4 waves of 64x64. Panels staged from PRE-CONVERTED
// bf16 z (d_ws). Epilogue: LDS transpose -> sigmoid -> nontemporal float4.
__global__ void __launch_bounds__(256) gemm_sig_kernel(
    const unsigned short* __restrict__ zb, float* __restrict__ out)
{
    // 2*128*SSTR shorts = 36864 B; epilogue reuses it as fp32 sC[64][CSTR]
    // (64*132*4 = 33792 B <= 36864 B).
    __shared__ __align__(16) unsigned short sAB[2 * 128 * SSTR];
    unsigned short* sA = sAB;
    unsigned short* sB = sAB + 128 * SSTR;

    int t    = threadIdx.x;
    int lane = t & 63;
    int wave = t >> 6;
    int wm = wave >> 1, wn = wave & 1;
    int j0 = blockIdx.x * 128;            // columns fast
    int i0 = blockIdx.y * 128;            // row band
    int l15  = lane & 15;
    int quad = lane >> 4;

    // ---- stage both 128-row bf16 panels into LDS ----
    #pragma unroll
    for (int pass = 0; pass < 4; ++pass) {
        int c   = pass * 256 + t;         // 0..1023
        int row = c >> 3;
        int c8  = (c & 7) << 3;           // ushort offset in row
        int ga = i0 + row; if (ga >= N_NODES) ga = N_NODES - 1;
        int gb = j0 + row; if (gb >= N_NODES) gb = N_NODES - 1;
        ushort8 va = *(const ushort8*)(zb + (size_t)ga * DIM_H + c8);
        ushort8 vb = *(const ushort8*)(zb + (size_t)gb * DIM_H + c8);
        *(ushort8*)(&sA[row * SSTR + c8]) = va;
        *(ushort8*)(&sB[row * SSTR + c8]) = vb;
    }
    __syncthreads();

    // ---- MFMA: each wave 64x64 = 4x4 frags, K=64 in two K=32 steps ----
    f32x4 acc[4][4];
    #pragma unroll
    for (int a = 0; a < 4; ++a)
        #pragma unroll
        for (int b = 0; b < 4; ++b) acc[a][b] = (f32x4)0.f;

    #pragma unroll
    for (int s = 0; s < 2; ++s) {
        int kb = quad * 8 + s * 32;               // A[m=lane&15][k=quad*8+j]
        short8 af[4], bfr[4];
        #pragma unroll
        for (int mi = 0; mi < 4; ++mi)
            af[mi] = *(const short8*)(&sA[(wm * 64 + mi * 16 + l15) * SSTR + kb]);
        #pragma unroll
        for (int ni = 0; ni < 4; ++ni)
            bfr[ni] = *(const short8*)(&sB[(wn * 64 + ni * 16 + l15) * SSTR + kb]);
        #pragma unroll
        for (int mi = 0; mi < 4; ++mi)
            #pragma unroll
            for (int ni = 0; ni < 4; ++ni)
                acc[mi][ni] = __builtin_amdgcn_mfma_f32_16x16x32_bf16(
                    af[mi], bfr[ni], acc[mi][ni], 0, 0, 0);
    }

    // ---- epilogue: LDS transpose -> sigmoid -> nontemporal float4 stores ----
    // C/D frag layout: col = lane&15, row = quad*4 + r.
    float* sC = (float*)sAB;
    #pragma unroll
    for (int half = 0; half < 2; ++half) {
        __syncthreads();   // prior LDS readers (frags / previous half) done
        if (wm == half) {
            #pragma unroll
            for (int mi = 0; mi < 4; ++mi)
                #pragma unroll
                for (int ni = 0; ni < 4; ++ni)
                    #pragma unroll
                    for (int r = 0; r < 4; ++r)
                        sC[(mi * 16 + quad * 4 + r) * CSTR + wn * 64 + ni * 16 + l15]
                            = acc[mi][ni][r];
        }
        __syncthreads();
        int i0h = i0 + half * 64;
        #pragma unroll
        for (int it = 0; it < 8; ++it) {
            int idx = it * 256 + t;           // 0..2047 over 64 rows x 32 float4
            int row = idx >> 5;
            int c4  = (idx & 31) << 2;
            f32x4 v = *(const f32x4*)&sC[row * CSTR + c4];
            f32x4 sg;
            sg.x = 1.0f / (1.0f + __expf(-v.x));
            sg.y = 1.0f / (1.0f + __expf(-v.y));
            sg.z = 1.0f / (1.0f + __expf(-v.z));
            sg.w = 1.0f / (1.0f + __expf(-v.w));
            int grow = i0h + row;
            int gcol = j0 + c4;
            if (grow < N_NODES && gcol + 3 < N_NODES) {   // N%4==0 -> float4-granular
                __builtin_nontemporal_store(
                    sg, (f32x4*)(out + (size_t)grow * N_NODES + gcol));
            }
        }
    }
}

extern "C" void kernel_launch(void* const* d_in, const int* in_sizes, int n_in,
                              void* d_out, int out_size, void* d_ws, size_t ws_size,
                              hipStream_t stream) {
    const float* x     = (const float*)d_in[0];  // [N,128] fp32
    const int*   ei    = (const int*)d_in[1];    // [2,E] int32
    const float* ew    = (const float*)d_in[2];  // [E] fp32
    const float* wrel  = (const float*)d_in[3];  // [128,64] fp32
    const float* wroot = (const float*)d_in[4];  // [128,64] fp32
    const float* bias  = (const float*)d_in[5];  // [64] fp32
    float* out = (float*)d_out;                  // fp32: adj [N*N] then z [N*64]

    // Scratch in d_ws (~9.1 MB of ~1.2 GB). Everything read is written first.
    char* base = (char*)d_ws;
    unsigned short* zb = (unsigned short*)(base);       // [N,64] bf16 z (1.28 MB)
    float* xr    = (float*)(base + 1280000);            // [N,64] f32 x@W_rel
    float* xw    = (float*)(base + 3840000);            // [N,64] f32 x@W_root + b
    int2* swsrt  = (int2*)(base + 6400000);             // E int2 packed {src,w}
    int* deg     = (int*)(base + 8960000);              // N ints
    int* offs    = (int*)(base + 9000000);              // N+1 ints
    int* cursor  = (int*)(base + 9040004);              // N ints

    void* pargs[] = {
        (void*)&x, (void*)&ei, (void*)&ew, (void*)&wrel, (void*)&wroot,
        (void*)&bias, (void*)&out, (void*)&zb, (void*)&xr, (void*)&xw,
        (void*)&swsrt, (void*)&deg, (void*)&offs, (void*)&cursor
    };
    (void)hipLaunchCooperativeKernel((void*)prologue_kernel,
                                     dim3(PBLOCKS), dim3(PTHREADS),
                                     pargs, 0, stream);

    dim3 grid((N_NODES + 127) / 128, (N_NODES + 127) / 128);  // x = cols, y = rows
    gemm_sig_kernel<<<grid, 256, 0, stream>>>(zb, out);
}

// Round 9
// 567.818 us; speedup vs baseline: 1.7269x; 1.7269x over previous
//
#include <hip/hip_runtime.h>
#include <hip/hip_bf16.h>
#include <stdint.h>

// GCNAE: N nodes, E edges, IN features, H hidden.
// Inputs fp32 (bf16-rounded values). Output fp32: adj [N,N] then z [N,H].
// R8 lesson: cg::grid().sync() costs ~140us each on MI355X (8 XCDs) -- the
// cooperative mega-fusion ran 570us at 1% BW, pure barrier idle. Kernel
// boundaries (~3us) are the cheap sync here. This round: separate kernels,
// with only barrier-FREE fusion (memset folded into feat; scan as a
// last-block-done tail of hist).
#define N_NODES 10000
#define N_EDGES 320000
#define DIM_IN  128
#define DIM_H   64
#define SSTR    72     // LDS row stride in shorts (64 + 8 pad -> 2-way banks only)
#define CSTR    132    // fp32 epilogue LDS stride (128 + 4 pad -> 2-way banks)

typedef __attribute__((ext_vector_type(8))) short  short8;   // 8 bf16 (MFMA A/B frag)
typedef __attribute__((ext_vector_type(8))) unsigned short ushort8;
typedef __attribute__((ext_vector_type(4))) float  f32x4;    // MFMA C/D frag + stores

__device__ __forceinline__ unsigned short f2bf(float f) {
    union { float f; unsigned int i; } v; v.f = f;
    unsigned int u = v.i;
    return (unsigned short)((u + 0x7fffu + ((u >> 16) & 1u)) >> 16);  // RNE
}

// ---- 1. feat: xr = x@W_rel, xw = x@W_root + b; also zeros deg/done --------
// (deg zeroing here replaces the hipMemsetAsync dispatch; stream order
// guarantees visibility to the following hist kernel.)
__global__ void __launch_bounds__(64) feat_kernel(
    const float* __restrict__ x,
    const float* __restrict__ wrel,
    const float* __restrict__ wroot,
    const float* __restrict__ bias,
    float* __restrict__ xr,                // [N,64] fp32
    float* __restrict__ xw,                // [N,64] fp32 (bias folded)
    int*   __restrict__ deg,
    int*   __restrict__ done)
{
    int i = blockIdx.x;
    int lane = threadIdx.x;
    if (lane == 0) deg[i] = 0;
    if (i == 0 && lane == 1) *done = 0;

    __shared__ float xL[DIM_IN];
    float2 xi = ((const float2*)(x + (size_t)i * DIM_IN))[lane];
    xL[2 * lane]     = xi.x;
    xL[2 * lane + 1] = xi.y;
    __syncthreads();

    float ar = 0.f, aw = bias[lane];
    for (int k = 0; k < DIM_IN; ++k) {
        float xv = xL[k];
        ar += xv * wrel[k * DIM_H + lane];
        aw += xv * wroot[k * DIM_H + lane];
    }
    xr[(size_t)i * DIM_H + lane] = ar;
    xw[(size_t)i * DIM_H + lane] = aw;
}

// ---- 2. hist + tail-block exclusive scan ----------------------------------
// Histogram of in-degrees; the LAST block to finish (device atomic counter,
// no grid.sync) performs the 256-thread scan. Tail block reads deg with
// atomicAdd(p,0) coherent reads (per-XCD L2s are not cross-coherent).
__global__ void __launch_bounds__(256) hist_scan_kernel(
    const int* __restrict__ ei, int* __restrict__ deg,
    int* __restrict__ offs, int* __restrict__ cursor,
    int* __restrict__ done)
{
    int t = threadIdx.x;
    int e = blockIdx.x * 256 + t;
    if (e < N_EDGES) atomicAdd(&deg[ei[N_EDGES + e]], 1);   // row 1 = dst
    __threadfence();

    __shared__ int isLast;
    if (t == 0) isLast = (atomicAdd(done, 1) == (int)gridDim.x - 1);
    __syncthreads();
    if (!isLast) return;

    // ---- tail: exclusive scan over deg -> offs, cursor (bit-identical
    // run-order to the R7/R8 scan) ----
    __shared__ int part[256];
    const int PER = 40;                   // 256*40 = 10240 >= N
    int base = t * PER;
    int s = 0;
    for (int k = 0; k < PER; ++k) {
        int idx = base + k;
        if (idx < N_NODES) s += atomicAdd(&deg[idx], 0);    // coherent read
    }
    part[t] = s;
    __syncthreads();
    for (int o = 1; o < 256; o <<= 1) {
        int add = (t >= o) ? part[t - o] : 0;
        __syncthreads();
        part[t] += add;
        __syncthreads();
    }
    int run = part[t] - s;
    for (int k = 0; k < PER; ++k) {
        int idx = base + k;
        if (idx < N_NODES) {
            int d = atomicAdd(&deg[idx], 0);                // coherent read
            offs[idx] = run; cursor[idx] = run; run += d;
        }
    }
    if (t == 255) offs[N_NODES] = part[255];
}

// ---- 3. bucket edges into CSR with PACKED payload -------------------------
__global__ void bucket_kernel(const int* __restrict__ ei,
                              const float* __restrict__ ew,
                              int* __restrict__ cursor,
                              int2* __restrict__ swsrt) {
    int e = blockIdx.x * blockDim.x + threadIdx.x;
    if (e < N_EDGES) {
        int d = ei[N_EDGES + e];
        int slot = atomicAdd(&cursor[d], 1);
        int2 pay;
        pay.x = ei[e];                       // src
        pay.y = __float_as_int(ew[e]);       // weight bits
        swsrt[slot] = pay;
    }
}

// ---- 4. per-node aggregate: z_i = sum_j w_ji*xr_j + xw_i ------------------
// Edge loop 4-wide (quarter-wave per edge, f32x4 per lane over 64 features):
// 256B gathers, 8 serial trips at avg degree 32, unroll-4 keeps ~16 gathers
// in flight per wave. Emits z fp32 (output) + bf16 (gemm staging).
__global__ void __launch_bounds__(64) agg_kernel(
    const float* __restrict__ xr,
    const float* __restrict__ xw,
    const int2* __restrict__ swsrt,
    const int* __restrict__ offs,
    float* __restrict__ out,               // d_out (fp32 z at N*N)
    unsigned short* __restrict__ zb)       // d_ws: z in bf16 [N,64]
{
    int i = blockIdx.x;
    int lane = threadIdx.x;
    int q   = lane >> 4;                   // edge slot 0..3
    int l16 = lane & 15;                   // feature quad id (16*4 = 64 feats)

    int beg = offs[i], end = offs[i + 1];
    f32x4 a = (f32x4)0.f;
    #pragma unroll 4
    for (int p = beg + q; p < end; p += 4) {
        int2 sw = swsrt[p];
        float w = __int_as_float(sw.y);
        f32x4 v = *(const f32x4*)(xr + (size_t)sw.x * DIM_H + l16 * 4);
        a += v * w;
    }
    // combine the 4 quarter-wave partials: butterfly over lane^16, lane^32.
    f32x4 b;
    b.x = __shfl_xor(a.x, 16); b.y = __shfl_xor(a.y, 16);
    b.z = __shfl_xor(a.z, 16); b.w = __shfl_xor(a.w, 16);
    a += b;
    b.x = __shfl_xor(a.x, 32); b.y = __shfl_xor(a.y, 32);
    b.z = __shfl_xor(a.z, 32); b.w = __shfl_xor(a.w, 32);
    a += b;

    if (q == 0) {
        f32x4 w4 = *(const f32x4*)(xw + (size_t)i * DIM_H + l16 * 4);
        f32x4 z4 = a + w4;
        *(f32x4*)(out + (size_t)N_NODES * N_NODES + (size_t)i * DIM_H + l16 * 4) = z4;
        ushort4 h;
        h.x = f2bf(z4.x); h.y = f2bf(z4.y); h.z = f2bf(z4.z); h.w = f2bf(z4.w);
        *(ushort4*)(zb + (size_t)i * DIM_H + l16 * 4) = h;
    }
}

// ---- 5. adj = sigmoid(z @ z^T) --------------------------------------------
// Block tile 128x128, 4 waves of 64x64. Panels staged from PRE-CONVERTED
// bf16 z (d_ws). Epilogue: LDS transpose -> sigmoid -> nontemporal float4.
__global__ void __launch_bounds__(256) gemm_sig_kernel(
    const unsigned short* __restrict__ zb, float* __restrict__ out)
{
    // 2*128*SSTR shorts = 36864 B; epilogue reuses it as fp32 sC[64][CSTR]
    // (64*132*4 = 33792 B <= 36864 B).
    __shared__ __align__(16) unsigned short sAB[2 * 128 * SSTR];
    unsigned short* sA = sAB;
    unsigned short* sB = sAB + 128 * SSTR;

    int t    = threadIdx.x;
    int lane = t & 63;
    int wave = t >> 6;
    int wm = wave >> 1, wn = wave & 1;
    int j0 = blockIdx.x * 128;            // columns fast
    int i0 = blockIdx.y * 128;            // row band
    int l15  = lane & 15;
    int quad = lane >> 4;

    // ---- stage both 128-row bf16 panels into LDS ----
    #pragma unroll
    for (int pass = 0; pass < 4; ++pass) {
        int c   = pass * 256 + t;         // 0..1023
        int row = c >> 3;
        int c8  = (c & 7) << 3;           // ushort offset in row
        int ga = i0 + row; if (ga >= N_NODES) ga = N_NODES - 1;
        int gb = j0 + row; if (gb >= N_NODES) gb = N_NODES - 1;
        ushort8 va = *(const ushort8*)(zb + (size_t)ga * DIM_H + c8);
        ushort8 vb = *(const ushort8*)(zb + (size_t)gb * DIM_H + c8);
        *(ushort8*)(&sA[row * SSTR + c8]) = va;
        *(ushort8*)(&sB[row * SSTR + c8]) = vb;
    }
    __syncthreads();

    // ---- MFMA: each wave 64x64 = 4x4 frags, K=64 in two K=32 steps ----
    f32x4 acc[4][4];
    #pragma unroll
    for (int a = 0; a < 4; ++a)
        #pragma unroll
        for (int b = 0; b < 4; ++b) acc[a][b] = (f32x4)0.f;

    #pragma unroll
    for (int s = 0; s < 2; ++s) {
        int kb = quad * 8 + s * 32;               // A[m=lane&15][k=quad*8+j]
        short8 af[4], bfr[4];
        #pragma unroll
        for (int mi = 0; mi < 4; ++mi)
            af[mi] = *(const short8*)(&sA[(wm * 64 + mi * 16 + l15) * SSTR + kb]);
        #pragma unroll
        for (int ni = 0; ni < 4; ++ni)
            bfr[ni] = *(const short8*)(&sB[(wn * 64 + ni * 16 + l15) * SSTR + kb]);
        #pragma unroll
        for (int mi = 0; mi < 4; ++mi)
            #pragma unroll
            for (int ni = 0; ni < 4; ++ni)
                acc[mi][ni] = __builtin_amdgcn_mfma_f32_16x16x32_bf16(
                    af[mi], bfr[ni], acc[mi][ni], 0, 0, 0);
    }

    // ---- epilogue: LDS transpose -> sigmoid -> nontemporal float4 stores ----
    // C/D frag layout: col = lane&15, row = quad*4 + r.
    float* sC = (float*)sAB;
    #pragma unroll
    for (int half = 0; half < 2; ++half) {
        __syncthreads();   // prior LDS readers (frags / previous half) done
        if (wm == half) {
            #pragma unroll
            for (int mi = 0; mi < 4; ++mi)
                #pragma unroll
                for (int ni = 0; ni < 4; ++ni)
                    #pragma unroll
                    for (int r = 0; r < 4; ++r)
                        sC[(mi * 16 + quad * 4 + r) * CSTR + wn * 64 + ni * 16 + l15]
                            = acc[mi][ni][r];
        }
        __syncthreads();
        int i0h = i0 + half * 64;
        #pragma unroll
        for (int it = 0; it < 8; ++it) {
            int idx = it * 256 + t;           // 0..2047 over 64 rows x 32 float4
            int row = idx >> 5;
            int c4  = (idx & 31) << 2;
            f32x4 v = *(const f32x4*)&sC[row * CSTR + c4];
            f32x4 sg;
            sg.x = 1.0f / (1.0f + __expf(-v.x));
            sg.y = 1.0f / (1.0f + __expf(-v.y));
            sg.z = 1.0f / (1.0f + __expf(-v.z));
            sg.w = 1.0f / (1.0f + __expf(-v.w));
            int grow = i0h + row;
            int gcol = j0 + c4;
            if (grow < N_NODES && gcol + 3 < N_NODES) {   // N%4==0 -> float4-granular
                __builtin_nontemporal_store(
                    sg, (f32x4*)(out + (size_t)grow * N_NODES + gcol));
            }
        }
    }
}

extern "C" void kernel_launch(void* const* d_in, const int* in_sizes, int n_in,
                              void* d_out, int out_size, void* d_ws, size_t ws_size,
                              hipStream_t stream) {
    const float* x     = (const float*)d_in[0];  // [N,128] fp32
    const int*   ei    = (const int*)d_in[1];    // [2,E] int32
    const float* ew    = (const float*)d_in[2];  // [E] fp32
    const float* wrel  = (const float*)d_in[3];  // [128,64] fp32
    const float* wroot = (const float*)d_in[4];  // [128,64] fp32
    const float* bias  = (const float*)d_in[5];  // [64] fp32
    float* out = (float*)d_out;                  // fp32: adj [N*N] then z [N*64]

    // Scratch in d_ws (~9.1 MB of ~1.2 GB). Everything read is written first.
    char* base = (char*)d_ws;
    unsigned short* zb = (unsigned short*)(base);       // [N,64] bf16 z (1.28 MB)
    float* xr    = (float*)(base + 1280000);            // [N,64] f32 x@W_rel
    float* xw    = (float*)(base + 3840000);            // [N,64] f32 x@W_root + b
    int2* swsrt  = (int2*)(base + 6400000);             // E int2 packed {src,w}
    int* deg     = (int*)(base + 8960000);              // N ints
    int* offs    = (int*)(base + 9000000);              // N+1 ints
    int* cursor  = (int*)(base + 9040004);              // N ints
    int* done    = (int*)(base + 9080004);              // 1 int

    feat_kernel<<<N_NODES, 64, 0, stream>>>(x, wrel, wroot, bias, xr, xw, deg, done);
    hist_scan_kernel<<<(N_EDGES + 255) / 256, 256, 0, stream>>>(ei, deg, offs,
                                                                cursor, done);
    bucket_kernel<<<(N_EDGES + 255) / 256, 256, 0, stream>>>(ei, ew, cursor, swsrt);
    agg_kernel<<<N_NODES, 64, 0, stream>>>(xr, xw, swsrt, offs, out, zb);
    dim3 grid((N_NODES + 127) / 128, (N_NODES + 127) / 128);  // x = cols, y = rows
    gemm_sig_kernel<<<grid, 256, 0, stream>>>(zb, out);
}

// Round 10
// 515.620 us; speedup vs baseline: 1.9018x; 1.1012x over previous
//
#include <hip/hip_runtime.h>
#include <hip/hip_bf16.h>
#include <stdint.h>

// GCNAE: N nodes, E edges, IN features, H hidden.
// Inputs fp32 (bf16-rounded values). Output fp32: adj [N,N] then z [N,H].
// R8 lesson: cg::grid().sync() ~140us each on MI355X -> never fuse via grid
// barriers. R9 lesson: per-thread __threadfence in hot kernels + atomic
// coherent-read scans cost ~68us -> only stream-order fusion is free.
// R10: symmetric gemm -- adj is symmetric; compute upper-triangle tile pairs
// only (3160 blocks vs 6241) and store each tile twice (normal + transposed).
#define N_NODES 10000
#define N_EDGES 320000
#define DIM_IN  128
#define DIM_H   64
#define NT      79     // number of 128-row tile bands: ceil(10000/128)
#define SSTR    72     // LDS row stride in shorts (64 + 8 pad -> 2-way banks only)
#define CSTR    133    // fp32 epilogue LDS stride (128 + 5: coprime w/ 32 banks
                       // -> stride-CSTR column reads for the mirror store ~2-way)

typedef __attribute__((ext_vector_type(8))) short  short8;   // 8 bf16 (MFMA A/B frag)
typedef __attribute__((ext_vector_type(8))) unsigned short ushort8;
typedef __attribute__((ext_vector_type(4))) float  f32x4;    // MFMA C/D frag + stores

__device__ __forceinline__ unsigned short f2bf(float f) {
    union { float f; unsigned int i; } v; v.f = f;
    unsigned int u = v.i;
    return (unsigned short)((u + 0x7fffu + ((u >> 16) & 1u)) >> 16);  // RNE
}

// ---- 1. feat: xr = x@W_rel, xw = x@W_root + b; zeros deg (stream-order) ---
__global__ void __launch_bounds__(64) feat_kernel(
    const float* __restrict__ x,
    const float* __restrict__ wrel,
    const float* __restrict__ wroot,
    const float* __restrict__ bias,
    float* __restrict__ xr,                // [N,64] fp32
    float* __restrict__ xw,                // [N,64] fp32 (bias folded)
    int*   __restrict__ deg)
{
    int i = blockIdx.x;
    int lane = threadIdx.x;
    if (lane == 0) deg[i] = 0;

    __shared__ float xL[DIM_IN];
    float2 xi = ((const float2*)(x + (size_t)i * DIM_IN))[lane];
    xL[2 * lane]     = xi.x;
    xL[2 * lane + 1] = xi.y;
    __syncthreads();

    float ar = 0.f, aw = bias[lane];
    for (int k = 0; k < DIM_IN; ++k) {
        float xv = xL[k];
        ar += xv * wrel[k * DIM_H + lane];
        aw += xv * wroot[k * DIM_H + lane];
    }
    xr[(size_t)i * DIM_H + lane] = ar;
    xw[(size_t)i * DIM_H + lane] = aw;
}

// ---- 2. histogram of in-degrees -------------------------------------------
__global__ void hist_kernel(const int* __restrict__ ei, int* __restrict__ deg) {
    int e = blockIdx.x * blockDim.x + threadIdx.x;
    if (e < N_EDGES) atomicAdd(&deg[ei[N_EDGES + e]], 1);   // row 1 = dst
}

// ---- 3. exclusive scan (single block, 1024 threads, 10 elems/thread) ------
__global__ void __launch_bounds__(1024) scan_kernel(const int* __restrict__ deg,
                                                    int* __restrict__ offs,
                                                    int* __restrict__ cursor) {
    __shared__ int part[1024];
    int t = threadIdx.x;
    int base = t * 10;
    int local[10];
    int s = 0;
    for (int i = 0; i < 10; ++i) {
        int idx = base + i;
        int d = (idx < N_NODES) ? deg[idx] : 0;
        local[i] = d; s += d;
    }
    part[t] = s;
    __syncthreads();
    for (int o = 1; o < 1024; o <<= 1) {
        int add = (t >= o) ? part[t - o] : 0;
        __syncthreads();
        part[t] += add;
        __syncthreads();
    }
    int run = part[t] - s;
    for (int i = 0; i < 10; ++i) {
        int idx = base + i;
        if (idx < N_NODES) { offs[idx] = run; cursor[idx] = run; run += local[i]; }
    }
    if (t == 1023) offs[N_NODES] = part[1023];
}

// ---- 4. bucket edges into CSR with PACKED payload -------------------------
__global__ void bucket_kernel(const int* __restrict__ ei,
                              const float* __restrict__ ew,
                              int* __restrict__ cursor,
                              int2* __restrict__ swsrt) {
    int e = blockIdx.x * blockDim.x + threadIdx.x;
    if (e < N_EDGES) {
        int d = ei[N_EDGES + e];
        int slot = atomicAdd(&cursor[d], 1);
        int2 pay;
        pay.x = ei[e];                       // src
        pay.y = __float_as_int(ew[e]);       // weight bits
        swsrt[slot] = pay;
    }
}

// ---- 5. per-node aggregate: z_i = sum_j w_ji*xr_j + xw_i ------------------
__global__ void __launch_bounds__(64) agg_kernel(
    const float* __restrict__ xr,
    const float* __restrict__ xw,
    const int2* __restrict__ swsrt,
    const int* __restrict__ offs,
    float* __restrict__ out,               // d_out (fp32 z at N*N)
    unsigned short* __restrict__ zb)       // d_ws: z in bf16 [N,64]
{
    int i = blockIdx.x;
    int lane = threadIdx.x;
    int q   = lane >> 4;                   // edge slot 0..3
    int l16 = lane & 15;                   // feature quad id (16*4 = 64 feats)

    int beg = offs[i], end = offs[i + 1];
    f32x4 a = (f32x4)0.f;
    #pragma unroll 4
    for (int p = beg + q; p < end; p += 4) {
        int2 sw = swsrt[p];
        float w = __int_as_float(sw.y);
        f32x4 v = *(const f32x4*)(xr + (size_t)sw.x * DIM_H + l16 * 4);
        a += v * w;
    }
    // combine the 4 quarter-wave partials: butterfly over lane^16, lane^32.
    f32x4 b;
    b.x = __shfl_xor(a.x, 16); b.y = __shfl_xor(a.y, 16);
    b.z = __shfl_xor(a.z, 16); b.w = __shfl_xor(a.w, 16);
    a += b;
    b.x = __shfl_xor(a.x, 32); b.y = __shfl_xor(a.y, 32);
    b.z = __shfl_xor(a.z, 32); b.w = __shfl_xor(a.w, 32);
    a += b;

    if (q == 0) {
        f32x4 w4 = *(const f32x4*)(xw + (size_t)i * DIM_H + l16 * 4);
        f32x4 z4 = a + w4;
        *(f32x4*)(out + (size_t)N_NODES * N_NODES + (size_t)i * DIM_H + l16 * 4) = z4;
        ushort4 h;
        h.x = f2bf(z4.x); h.y = f2bf(z4.y); h.z = f2bf(z4.z); h.w = f2bf(z4.w);
        *(ushort4*)(zb + (size_t)i * DIM_H + l16 * 4) = h;
    }
}

// ---- 6. adj = sigmoid(z @ z^T), SYMMETRIC ---------------------------------
// Grid = 3160 upper-triangle tile pairs (bi<=bj). Each block computes one
// 128x128 tile and stores it at (bi,bj) row-major AND (bj,bi) transposed
// (sC column reads; CSTR=133 keeps them ~2-way on 32 banks). Halves MFMA,
// staging, and block count; store bytes unchanged (= the HBM floor).
__global__ void __launch_bounds__(256) gemm_sig_kernel(
    const unsigned short* __restrict__ zb, float* __restrict__ out)
{
    // 2*128*SSTR shorts = 36864 B; epilogue reuses it as fp32 sC[64][CSTR]
    // (64*133*4 = 34048 B <= 36864 B).
    __shared__ __align__(16) unsigned short sAB[2 * 128 * SSTR];
    unsigned short* sA = sAB;
    unsigned short* sB = sAB + 128 * SSTR;

    int t    = threadIdx.x;
    int lane = t & 63;
    int wave = t >> 6;
    int wm = wave >> 1, wn = wave & 1;
    int l15  = lane & 15;
    int quad = lane >> 4;

    // ---- decode upper-triangle pair: bid -> (bi, bj), bi<=bj ----
    int bid = blockIdx.x;
    int bi = (int)floorf((float)NT + 0.5f -
                         sqrtf(((float)NT + 0.5f) * ((float)NT + 0.5f) - 2.0f * bid));
    if (bi < 0) bi = 0;
    while (bi * NT - bi * (bi - 1) / 2 > bid) --bi;
    while ((bi + 1) * NT - (bi + 1) * bi / 2 <= bid) ++bi;
    int bj = bi + (bid - (bi * NT - bi * (bi - 1) / 2));
    int i0 = bi * 128;
    int j0 = bj * 128;

    // ---- stage both 128-row bf16 panels into LDS ----
    #pragma unroll
    for (int pass = 0; pass < 4; ++pass) {
        int c   = pass * 256 + t;         // 0..1023
        int row = c >> 3;
        int c8  = (c & 7) << 3;           // ushort offset in row
        int ga = i0 + row; if (ga >= N_NODES) ga = N_NODES - 1;
        int gb = j0 + row; if (gb >= N_NODES) gb = N_NODES - 1;
        ushort8 va = *(const ushort8*)(zb + (size_t)ga * DIM_H + c8);
        ushort8 vb = *(const ushort8*)(zb + (size_t)gb * DIM_H + c8);
        *(ushort8*)(&sA[row * SSTR + c8]) = va;
        *(ushort8*)(&sB[row * SSTR + c8]) = vb;
    }
    __syncthreads();

    // ---- MFMA: each wave 64x64 = 4x4 frags, K=64 in two K=32 steps ----
    f32x4 acc[4][4];
    #pragma unroll
    for (int a = 0; a < 4; ++a)
        #pragma unroll
        for (int b = 0; b < 4; ++b) acc[a][b] = (f32x4)0.f;

    #pragma unroll
    for (int s = 0; s < 2; ++s) {
        int kb = quad * 8 + s * 32;               // A[m=lane&15][k=quad*8+j]
        short8 af[4], bfr[4];
        #pragma unroll
        for (int mi = 0; mi < 4; ++mi)
            af[mi] = *(const short8*)(&sA[(wm * 64 + mi * 16 + l15) * SSTR + kb]);
        #pragma unroll
        for (int ni = 0; ni < 4; ++ni)
            bfr[ni] = *(const short8*)(&sB[(wn * 64 + ni * 16 + l15) * SSTR + kb]);
        #pragma unroll
        for (int mi = 0; mi < 4; ++mi)
            #pragma unroll
            for (int ni = 0; ni < 4; ++ni)
                acc[mi][ni] = __builtin_amdgcn_mfma_f32_16x16x32_bf16(
                    af[mi], bfr[ni], acc[mi][ni], 0, 0, 0);
    }

    // ---- epilogue: LDS transpose -> sigmoid -> nontemporal float4 stores ----
    // C/D frag layout: col = lane&15, row = quad*4 + r.
    float* sC = (float*)sAB;
    #pragma unroll
    for (int half = 0; half < 2; ++half) {
        __syncthreads();   // prior LDS readers (frags / previous half) done
        if (wm == half) {
            #pragma unroll
            for (int mi = 0; mi < 4; ++mi)
                #pragma unroll
                for (int ni = 0; ni < 4; ++ni)
                    #pragma unroll
                    for (int r = 0; r < 4; ++r)
                        sC[(mi * 16 + quad * 4 + r) * CSTR + wn * 64 + ni * 16 + l15]
                            = acc[mi][ni][r];
        }
        __syncthreads();
        int i0h = i0 + half * 64;

        // normal store: rows i0h..i0h+63, cols j0..j0+127
        #pragma unroll
        for (int it = 0; it < 8; ++it) {
            int idx = it * 256 + t;           // 0..2047 over 64 rows x 32 float4
            int row = idx >> 5;
            int c4  = (idx & 31) << 2;
            f32x4 v = *(const f32x4*)&sC[row * CSTR + c4];
            f32x4 sg;
            sg.x = 1.0f / (1.0f + __expf(-v.x));
            sg.y = 1.0f / (1.0f + __expf(-v.y));
            sg.z = 1.0f / (1.0f + __expf(-v.z));
            sg.w = 1.0f / (1.0f + __expf(-v.w));
            int grow = i0h + row;
            int gcol = j0 + c4;
            if (grow < N_NODES && gcol + 3 < N_NODES) {   // N%4==0 -> float4-granular
                __builtin_nontemporal_store(
                    sg, (f32x4*)(out + (size_t)grow * N_NODES + gcol));
            }
        }

        // mirror store (bi!=bj): rows j0..j0+127, cols i0h..i0h+63
        if (bi != bj) {
            #pragma unroll
            for (int it = 0; it < 8; ++it) {
                int idx  = it * 256 + t;      // 0..2047 over 128 rows x 16 float4
                int mrow = idx >> 4;          // 0..127 (col j of tile)
                int mc4  = (idx & 15) << 2;   // 0..60  (row i of half)
                f32x4 v;
                v.x = sC[(mc4 + 0) * CSTR + mrow];
                v.y = sC[(mc4 + 1) * CSTR + mrow];
                v.z = sC[(mc4 + 2) * CSTR + mrow];
                v.w = sC[(mc4 + 3) * CSTR + mrow];
                f32x4 sg;
                sg.x = 1.0f / (1.0f + __expf(-v.x));
                sg.y = 1.0f / (1.0f + __expf(-v.y));
                sg.z = 1.0f / (1.0f + __expf(-v.z));
                sg.w = 1.0f / (1.0f + __expf(-v.w));
                int grow = j0 + mrow;
                int gcol = i0h + mc4;
                if (grow < N_NODES && gcol + 3 < N_NODES) {
                    __builtin_nontemporal_store(
                        sg, (f32x4*)(out + (size_t)grow * N_NODES + gcol));
                }
            }
        }
    }
}

extern "C" void kernel_launch(void* const* d_in, const int* in_sizes, int n_in,
                              void* d_out, int out_size, void* d_ws, size_t ws_size,
                              hipStream_t stream) {
    const float* x     = (const float*)d_in[0];  // [N,128] fp32
    const int*   ei    = (const int*)d_in[1];    // [2,E] int32
    const float* ew    = (const float*)d_in[2];  // [E] fp32
    const float* wrel  = (const float*)d_in[3];  // [128,64] fp32
    const float* wroot = (const float*)d_in[4];  // [128,64] fp32
    const float* bias  = (const float*)d_in[5];  // [64] fp32
    float* out = (float*)d_out;                  // fp32: adj [N*N] then z [N*64]

    // Scratch in d_ws (~9.1 MB of ~1.2 GB). Everything read is written first.
    char* base = (char*)d_ws;
    unsigned short* zb = (unsigned short*)(base);       // [N,64] bf16 z (1.28 MB)
    float* xr    = (float*)(base + 1280000);            // [N,64] f32 x@W_rel
    float* xw    = (float*)(base + 3840000);            // [N,64] f32 x@W_root + b
    int2* swsrt  = (int2*)(base + 6400000);             // E int2 packed {src,w}
    int* deg     = (int*)(base + 8960000);              // N ints
    int* offs    = (int*)(base + 9000000);              // N+1 ints
    int* cursor  = (int*)(base + 9040004);              // N ints

    feat_kernel<<<N_NODES, 64, 0, stream>>>(x, wrel, wroot, bias, xr, xw, deg);
    hist_kernel<<<(N_EDGES + 255) / 256, 256, 0, stream>>>(ei, deg);
    scan_kernel<<<1, 1024, 0, stream>>>(deg, offs, cursor);
    bucket_kernel<<<(N_EDGES + 255) / 256, 256, 0, stream>>>(ei, ew, cursor, swsrt);
    agg_kernel<<<N_NODES, 64, 0, stream>>>(xr, xw, swsrt, offs, out, zb);
    gemm_sig_kernel<<<NT * (NT + 1) / 2, 256, 0, stream>>>(zb, out);
}

// Round 11
// 499.283 us; speedup vs baseline: 1.9640x; 1.0327x over previous
//
#include <hip/hip_runtime.h>
#include <hip/hip_bf16.h>
#include <stdint.h>

// GCNAE: N nodes, E edges, IN features, H hidden.
// Inputs fp32 (bf16-rounded values). Output fp32: adj [N,N] then z [N,H].
// Session ledger:
//  R8: cg::grid().sync() ~140us each on MI355X -> never fuse via grid barrier.
//  R9: per-thread __threadfence in hot kernels costs ~68us -> only
//      stream-order fusion is free.
//  R10: symmetric (upper-triangle) gemm regressed +16us -> gemm is not
//      compute-bound; mirror store path costs more than halved MFMA saves.
//  R11: revert to R7 structure (best: 499.6us) + keep memset folded into feat.
#define N_NODES 10000
#define N_EDGES 320000
#define DIM_IN  128
#define DIM_H   64
#define SSTR    72     // LDS row stride in shorts (64 + 8 pad -> 2-way banks only)
#define CSTR    132    // fp32 epilogue LDS stride (128 + 4 pad -> 2-way banks)

typedef __attribute__((ext_vector_type(8))) short  short8;   // 8 bf16 (MFMA A/B frag)
typedef __attribute__((ext_vector_type(8))) unsigned short ushort8;
typedef __attribute__((ext_vector_type(4))) float  f32x4;    // MFMA C/D frag + stores

__device__ __forceinline__ unsigned short f2bf(float f) {
    union { float f; unsigned int i; } v; v.f = f;
    unsigned int u = v.i;
    return (unsigned short)((u + 0x7fffu + ((u >> 16) & 1u)) >> 16);  // RNE
}

// ---- 1. feat: xr = x@W_rel, xw = x@W_root + b; zeros deg (stream-order) ---
__global__ void __launch_bounds__(64) feat_kernel(
    const float* __restrict__ x,
    const float* __restrict__ wrel,
    const float* __restrict__ wroot,
    const float* __restrict__ bias,
    float* __restrict__ xr,                // [N,64] fp32
    float* __restrict__ xw,                // [N,64] fp32 (bias folded)
    int*   __restrict__ deg)
{
    int i = blockIdx.x;
    int lane = threadIdx.x;
    if (lane == 0) deg[i] = 0;

    __shared__ float xL[DIM_IN];
    float2 xi = ((const float2*)(x + (size_t)i * DIM_IN))[lane];
    xL[2 * lane]     = xi.x;
    xL[2 * lane + 1] = xi.y;
    __syncthreads();

    float ar = 0.f, aw = bias[lane];
    for (int k = 0; k < DIM_IN; ++k) {
        float xv = xL[k];
        ar += xv * wrel[k * DIM_H + lane];
        aw += xv * wroot[k * DIM_H + lane];
    }
    xr[(size_t)i * DIM_H + lane] = ar;
    xw[(size_t)i * DIM_H + lane] = aw;
}

// ---- 2. histogram of in-degrees -------------------------------------------
__global__ void hist_kernel(const int* __restrict__ ei, int* __restrict__ deg) {
    int e = blockIdx.x * blockDim.x + threadIdx.x;
    if (e < N_EDGES) atomicAdd(&deg[ei[N_EDGES + e]], 1);   // row 1 = dst
}

// ---- 3. exclusive scan (single block, 1024 threads, 10 elems/thread) ------
__global__ void __launch_bounds__(1024) scan_kernel(const int* __restrict__ deg,
                                                    int* __restrict__ offs,
                                                    int* __restrict__ cursor) {
    __shared__ int part[1024];
    int t = threadIdx.x;
    int base = t * 10;
    int local[10];
    int s = 0;
    for (int i = 0; i < 10; ++i) {
        int idx = base + i;
        int d = (idx < N_NODES) ? deg[idx] : 0;
        local[i] = d; s += d;
    }
    part[t] = s;
    __syncthreads();
    for (int o = 1; o < 1024; o <<= 1) {
        int add = (t >= o) ? part[t - o] : 0;
        __syncthreads();
        part[t] += add;
        __syncthreads();
    }
    int run = part[t] - s;
    for (int i = 0; i < 10; ++i) {
        int idx = base + i;
        if (idx < N_NODES) { offs[idx] = run; cursor[idx] = run; run += local[i]; }
    }
    if (t == 1023) offs[N_NODES] = part[1023];
}

// ---- 4. bucket edges into CSR with PACKED payload -------------------------
__global__ void bucket_kernel(const int* __restrict__ ei,
                              const float* __restrict__ ew,
                              int* __restrict__ cursor,
                              int2* __restrict__ swsrt) {
    int e = blockIdx.x * blockDim.x + threadIdx.x;
    if (e < N_EDGES) {
        int d = ei[N_EDGES + e];
        int slot = atomicAdd(&cursor[d], 1);
        int2 pay;
        pay.x = ei[e];                       // src
        pay.y = __float_as_int(ew[e]);       // weight bits
        swsrt[slot] = pay;
    }
}

// ---- 5. per-node aggregate: z_i = sum_j w_ji*xr_j + xw_i ------------------
// Edge loop 4-wide (quarter-wave per edge, f32x4 per lane over 64 features):
// 256B gathers (L2-served: xr is 2.56MB), unroll-4 keeps ~16 gathers in
// flight per wave. Emits z fp32 (output) + bf16 (gemm staging).
__global__ void __launch_bounds__(64) agg_kernel(
    const float* __restrict__ xr,
    const float* __restrict__ xw,
    const int2* __restrict__ swsrt,
    const int* __restrict__ offs,
    float* __restrict__ out,               // d_out (fp32 z at N*N)
    unsigned short* __restrict__ zb)       // d_ws: z in bf16 [N,64]
{
    int i = blockIdx.x;
    int lane = threadIdx.x;
    int q   = lane >> 4;                   // edge slot 0..3
    int l16 = lane & 15;                   // feature quad id (16*4 = 64 feats)

    int beg = offs[i], end = offs[i + 1];
    f32x4 a = (f32x4)0.f;
    #pragma unroll 4
    for (int p = beg + q; p < end; p += 4) {
        int2 sw = swsrt[p];
        float w = __int_as_float(sw.y);
        f32x4 v = *(const f32x4*)(xr + (size_t)sw.x * DIM_H + l16 * 4);
        a += v * w;
    }
    // combine the 4 quarter-wave partials: butterfly over lane^16, lane^32.
    f32x4 b;
    b.x = __shfl_xor(a.x, 16); b.y = __shfl_xor(a.y, 16);
    b.z = __shfl_xor(a.z, 16); b.w = __shfl_xor(a.w, 16);
    a += b;
    b.x = __shfl_xor(a.x, 32); b.y = __shfl_xor(a.y, 32);
    b.z = __shfl_xor(a.z, 32); b.w = __shfl_xor(a.w, 32);
    a += b;

    if (q == 0) {
        f32x4 w4 = *(const f32x4*)(xw + (size_t)i * DIM_H + l16 * 4);
        f32x4 z4 = a + w4;
        *(f32x4*)(out + (size_t)N_NODES * N_NODES + (size_t)i * DIM_H + l16 * 4) = z4;
        ushort4 h;
        h.x = f2bf(z4.x); h.y = f2bf(z4.y); h.z = f2bf(z4.z); h.w = f2bf(z4.w);
        *(ushort4*)(zb + (size_t)i * DIM_H + l16 * 4) = h;
    }
}

// ---- 6. adj = sigmoid(z @ z^T) --------------------------------------------
// Block tile 128x128, 4 waves of 64x64. Panels staged from PRE-CONVERTED
// bf16 z (d_ws). Epilogue: LDS transpose -> sigmoid -> nontemporal float4.
// (R10's symmetric variant regressed; full grid restored.)
__global__ void __launch_bounds__(256) gemm_sig_kernel(
    const unsigned short* __restrict__ zb, float* __restrict__ out)
{
    // 2*128*SSTR shorts = 36864 B; epilogue reuses it as fp32 sC[64][CSTR]
    // (64*132*4 = 33792 B <= 36864 B).
    __shared__ __align__(16) unsigned short sAB[2 * 128 * SSTR];
    unsigned short* sA = sAB;
    unsigned short* sB = sAB + 128 * SSTR;

    int t    = threadIdx.x;
    int lane = t & 63;
    int wave = t >> 6;
    int wm = wave >> 1, wn = wave & 1;
    int j0 = blockIdx.x * 128;            // columns fast
    int i0 = blockIdx.y * 128;            // row band
    int l15  = lane & 15;
    int quad = lane >> 4;

    // ---- stage both 128-row bf16 panels into LDS ----
    #pragma unroll
    for (int pass = 0; pass < 4; ++pass) {
        int c   = pass * 256 + t;         // 0..1023
        int row = c >> 3;
        int c8  = (c & 7) << 3;           // ushort offset in row
        int ga = i0 + row; if (ga >= N_NODES) ga = N_NODES - 1;
        int gb = j0 + row; if (gb >= N_NODES) gb = N_NODES - 1;
        ushort8 va = *(const ushort8*)(zb + (size_t)ga * DIM_H + c8);
        ushort8 vb = *(const ushort8*)(zb + (size_t)gb * DIM_H + c8);
        *(ushort8*)(&sA[row * SSTR + c8]) = va;
        *(ushort8*)(&sB[row * SSTR + c8]) = vb;
    }
    __syncthreads();

    // ---- MFMA: each wave 64x64 = 4x4 frags, K=64 in two K=32 steps ----
    f32x4 acc[4][4];
    #pragma unroll
    for (int a = 0; a < 4; ++a)
        #pragma unroll
        for (int b = 0; b < 4; ++b) acc[a][b] = (f32x4)0.f;

    #pragma unroll
    for (int s = 0; s < 2; ++s) {
        int kb = quad * 8 + s * 32;               // A[m=lane&15][k=quad*8+j]
        short8 af[4], bfr[4];
        #pragma unroll
        for (int mi = 0; mi < 4; ++mi)
            af[mi] = *(const short8*)(&sA[(wm * 64 + mi * 16 + l15) * SSTR + kb]);
        #pragma unroll
        for (int ni = 0; ni < 4; ++ni)
            bfr[ni] = *(const short8*)(&sB[(wn * 64 + ni * 16 + l15) * SSTR + kb]);
        #pragma unroll
        for (int mi = 0; mi < 4; ++mi)
            #pragma unroll
            for (int ni = 0; ni < 4; ++ni)
                acc[mi][ni] = __builtin_amdgcn_mfma_f32_16x16x32_bf16(
                    af[mi], bfr[ni], acc[mi][ni], 0, 0, 0);
    }

    // ---- epilogue: LDS transpose -> sigmoid -> nontemporal float4 stores ----
    // C/D frag layout: col = lane&15, row = quad*4 + r.
    float* sC = (float*)sAB;
    #pragma unroll
    for (int half = 0; half < 2; ++half) {
        __syncthreads();   // prior LDS readers (frags / previous half) done
        if (wm == half) {
            #pragma unroll
            for (int mi = 0; mi < 4; ++mi)
                #pragma unroll
                for (int ni = 0; ni < 4; ++ni)
                    #pragma unroll
                    for (int r = 0; r < 4; ++r)
                        sC[(mi * 16 + quad * 4 + r) * CSTR + wn * 64 + ni * 16 + l15]
                            = acc[mi][ni][r];
        }
        __syncthreads();
        int i0h = i0 + half * 64;
        #pragma unroll
        for (int it = 0; it < 8; ++it) {
            int idx = it * 256 + t;           // 0..2047 over 64 rows x 32 float4
            int row = idx >> 5;
            int c4  = (idx & 31) << 2;
            f32x4 v = *(const f32x4*)&sC[row * CSTR + c4];
            f32x4 sg;
            sg.x = 1.0f / (1.0f + __expf(-v.x));
            sg.y = 1.0f / (1.0f + __expf(-v.y));
            sg.z = 1.0f / (1.0f + __expf(-v.z));
            sg.w = 1.0f / (1.0f + __expf(-v.w));
            int grow = i0h + row;
            int gcol = j0 + c4;
            if (grow < N_NODES && gcol + 3 < N_NODES) {   // N%4==0 -> float4-granular
                __builtin_nontemporal_store(
                    sg, (f32x4*)(out + (size_t)grow * N_NODES + gcol));
            }
        }
    }
}

extern "C" void kernel_launch(void* const* d_in, const int* in_sizes, int n_in,
                              void* d_out, int out_size, void* d_ws, size_t ws_size,
                              hipStream_t stream) {
    const float* x     = (const float*)d_in[0];  // [N,128] fp32
    const int*   ei    = (const int*)d_in[1];    // [2,E] int32
    const float* ew    = (const float*)d_in[2];  // [E] fp32
    const float* wrel  = (const float*)d_in[3];  // [128,64] fp32
    const float* wroot = (const float*)d_in[4];  // [128,64] fp32
    const float* bias  = (const float*)d_in[5];  // [64] fp32
    float* out = (float*)d_out;                  // fp32: adj [N*N] then z [N*64]

    // Scratch in d_ws (~9.1 MB of ~1.2 GB). Everything read is written first.
    char* base = (char*)d_ws;
    unsigned short* zb = (unsigned short*)(base);       // [N,64] bf16 z (1.28 MB)
    float* xr    = (float*)(base + 1280000);            // [N,64] f32 x@W_rel
    float* xw    = (float*)(base + 3840000);            // [N,64] f32 x@W_root + b
    int2* swsrt  = (int2*)(base + 6400000);             // E int2 packed {src,w}
    int* deg     = (int*)(base + 8960000);              // N ints
    int* offs    = (int*)(base + 9000000);              // N+1 ints
    int* cursor  = (int*)(base + 9040004);              // N ints

    feat_kernel<<<N_NODES, 64, 0, stream>>>(x, wrel, wroot, bias, xr, xw, deg);
    hist_kernel<<<(N_EDGES + 255) / 256, 256, 0, stream>>>(ei, deg);
    scan_kernel<<<1, 1024, 0, stream>>>(deg, offs, cursor);
    bucket_kernel<<<(N_EDGES + 255) / 256, 256, 0, stream>>>(ei, ew, cursor, swsrt);
    agg_kernel<<<N_NODES, 64, 0, stream>>>(xr, xw, swsrt, offs, out, zb);
    dim3 grid((N_NODES + 127) / 128, (N_NODES + 127) / 128);  // x = cols, y = rows
    gemm_sig_kernel<<<grid, 256, 0, stream>>>(zb, out);
}